// Round 4
// baseline (380.975 us; speedup 1.0000x reference)
//
#include <hip/hip_runtime.h>
#include <hip/hip_bf16.h>
#include <stdint.h>
#include <math.h>

// Problem constants (fixed by reference)
#define NROWS   32768      // 8*4096
#define CDIM    768
#define NCODES  2048
#define BM      64         // rows per block (A-tile resident in LDS)
#define KSTEPS  24         // 768 / 32 (K per MFMA)
#define ESCALE  2048.0f    // 2^11: lifts e into e4m3 range
#define INV2ESCALE (2.0f / ESCALE)

typedef __attribute__((ext_vector_type(4))) float f32x4;

// ---------- helpers ----------
__device__ __forceinline__ void async_load16(const void* gsrc, void* ldst) {
    __builtin_amdgcn_global_load_lds(
        (const __attribute__((address_space(1))) unsigned int*)gsrc,
        (__attribute__((address_space(3))) unsigned int*)ldst,
        16 /*bytes*/, 0 /*offset*/, 0 /*aux*/);
}

__device__ __forceinline__ unsigned int pack4_fp8(float x, float y, float z, float w) {
    int v = __builtin_amdgcn_cvt_pk_fp8_f32(x, y, 0, false);   // bytes 0,1
    v     = __builtin_amdgcn_cvt_pk_fp8_f32(z, w, v, true);    // bytes 2,3
    return (unsigned int)v;
}

// ---------- 1) fused: z -> fp8 (row-major)  AND  e -> fp8*2048 K-major + ||e||^2 + zero hist ----
// e8t layout: [KSTEPS][NCODES][32] bytes — granule (s24, col) holds e[col][s24*32 .. +32].
#define ZBLOCKS 6144       // 25165824 elems / (256 thr * 16 elem)
__global__ __launch_bounds__(256) void convert_fused(const float* __restrict__ z,
                                                     const float* __restrict__ e,
                                                     unsigned char* __restrict__ z8,
                                                     unsigned char* __restrict__ e8t,
                                                     float* __restrict__ enorm,
                                                     unsigned int* __restrict__ counts) {
    int b = blockIdx.x;
    if (b < ZBLOCKS) {
        int i = b * 256 + threadIdx.x;            // 16 floats per thread, grid exact
        const float4* zp = (const float4*)z;
        float4 a0 = zp[4 * i + 0];
        float4 a1 = zp[4 * i + 1];
        float4 a2 = zp[4 * i + 2];
        float4 a3 = zp[4 * i + 3];
        uint4 o;
        o.x = pack4_fp8(a0.x, a0.y, a0.z, a0.w);
        o.y = pack4_fp8(a1.x, a1.y, a1.z, a1.w);
        o.z = pack4_fp8(a2.x, a2.y, a2.z, a2.w);
        o.w = pack4_fp8(a3.x, a3.y, a3.z, a3.w);
        ((uint4*)z8)[i] = o;
    } else {
        int k = b - ZBLOCKS;                      // one code per block
        int t = threadIdx.x;
        float s = 0.f;
        if (t < 192) {                            // 192 * 4 = 768 elems
            float4 v = ((const float4*)(e + (size_t)k * CDIM))[t];
            s = v.x * v.x + v.y * v.y + v.z * v.z + v.w * v.w;
            unsigned int pk = pack4_fp8(v.x * ESCALE, v.y * ESCALE,
                                        v.z * ESCALE, v.w * ESCALE);
            int s24 = t >> 3;                     // k-step of this float4
            int dw  = t & 7;                      // dword within 32B granule
            ((unsigned int*)(e8t + (size_t)s24 * (NCODES * 32) + (size_t)k * 32))[dw] = pk;
        }
        #pragma unroll
        for (int o = 32; o > 0; o >>= 1) s += __shfl_down(s, o);
        __shared__ float red[4];
        if ((t & 63) == 0) red[t >> 6] = s;
        __syncthreads();
        if (t == 0) {
            enorm[k] = red[0] + red[1] + red[2] + red[3];
            counts[k] = 0u;
        }
    }
}

// ---------- 2) A-resident fp8 GEMM + argmin + gather + histogram (barrier-free K-loop) ----------
// Block owns rows m0..m0+64. A-tile staged to LDS ONCE (48 KB, XOR-swizzled granules),
// then each wave sweeps its own 512 cols with zero __syncthreads in the K-loop:
// A frags from LDS (bank-floor b64), B frags coalesced b64 straight from L2 (e8t K-major).
// score = ||e_k||^2 - (2/2048) * dotE;  per-lane running argmin, one reduction at end.
__global__ __launch_bounds__(256, 2) void gemm_fused(const unsigned char* __restrict__ z8,
                                                     const unsigned char* __restrict__ e8t,
                                                     const float* __restrict__ enorm,
                                                     const float* __restrict__ e,
                                                     float* __restrict__ out,
                                                     unsigned int* __restrict__ counts) {
    __shared__ __align__(16) unsigned char As[BM * CDIM];   // 48 KB
    __shared__ float s_en[NCODES];                          // 8 KB
    __shared__ float s_bv[4][BM];
    __shared__ int   s_bi[4][BM];

    const int tid  = threadIdx.x;
    const int m0   = blockIdx.x * BM;
    const int lane = tid & 63;
    const int w    = tid >> 6;
    const int quad = lane >> 4;
    const int l16  = lane & 15;

    // --- stage A-tile: 3072 granules of 16B; slot (kb*64+r)*4 + (g ^ (r&3)) holds
    //     z8[m0+r][kb*64 + g*16 .. +16]  (wave-uniform base + lane*16 respected) ---
    #pragma unroll
    for (int t2 = 0; t2 < 12; ++t2) {
        int s  = t2 * 256 + tid;
        int rb = s >> 2;
        int r  = rb & (BM - 1);
        int kb = rb >> 6;                // 0..11
        int g  = (s & 3) ^ (r & 3);
        async_load16(z8 + (size_t)(m0 + r) * CDIM + kb * 64 + g * 16, &As[s * 16]);
    }
    #pragma unroll
    for (int t2 = 0; t2 < 8; ++t2)
        s_en[t2 * 256 + tid] = enorm[t2 * 256 + tid];
    __syncthreads();                     // the ONLY barrier before the epilogue

    const int wcol0 = w * 512;           // each wave owns 512 cols, 8 chunks of 64
    float rv[16];
    int   ri[16];
    #pragma unroll
    for (int p = 0; p < 16; ++p) { rv[p] = 1e30f; ri[p] = 0; }

    for (int chunk = 0; chunk < 8; ++chunk) {
        const int c0 = wcol0 + chunk * 64;
        f32x4 acc[4][4] = {};
        long a0[4], a1[4], b0[4], b1[4];

        // A frag: row = i*16+l16; k-block kb=s24>>1; granule g=(s24&1)*2+(quad>>1);
        //         swizzled pos = g ^ (row&3); +8B half per quad parity.
        #define LOADA(dst, s24) { int kb = (s24) >> 1; int gg = ((s24) & 1) * 2 + (quad >> 1); \
            _Pragma("unroll") for (int i = 0; i < 4; ++i) { int row = i * 16 + l16; \
              dst[i] = *(const long*)&As[(size_t)((kb * BM + row) * 4 + (gg ^ (row & 3))) * 16 + (quad & 1) * 8]; } }
        // B frag: contiguous 512B per (j) wave-load from K-major e8t.
        #define LOADB(dst, s24) { const unsigned char* bp = e8t + (size_t)(s24) * (NCODES * 32) \
                + (size_t)c0 * 32 + l16 * 32 + quad * 8; \
            _Pragma("unroll") for (int j = 0; j < 4; ++j) dst[j] = *(const long*)(bp + j * 512); }
        #define MFMA16(a, b) _Pragma("unroll") for (int i = 0; i < 4; ++i) \
            _Pragma("unroll") for (int j = 0; j < 4; ++j) \
              acc[i][j] = __builtin_amdgcn_mfma_f32_16x16x32_fp8_fp8(a[i], b[j], acc[i][j], 0, 0, 0);

        LOADA(a0, 0); LOADB(b0, 0);
        #pragma unroll
        for (int s24 = 0; s24 < KSTEPS; s24 += 2) {
            LOADA(a1, s24 + 1); LOADB(b1, s24 + 1);
            MFMA16(a0, b0);
            if (s24 + 2 < KSTEPS) { LOADA(a0, s24 + 2); LOADB(b0, s24 + 2); }
            MFMA16(a1, b1);
        }
        #undef LOADA
        #undef LOADB
        #undef MFMA16

        // per-chunk epilogue: per-lane select only
        float en[4];
        #pragma unroll
        for (int j = 0; j < 4; ++j) en[j] = s_en[c0 + j * 16 + l16];
        const int colbase = c0 + l16;
        #pragma unroll
        for (int i = 0; i < 4; ++i) {
            #pragma unroll
            for (int r = 0; r < 4; ++r) {
                float v   = fmaf(-INV2ESCALE, acc[i][0][r], en[0]);
                int   idx = colbase;
                #pragma unroll
                for (int j = 1; j < 4; ++j) {
                    float v2 = fmaf(-INV2ESCALE, acc[i][j][r], en[j]);
                    int   i2 = colbase + j * 16;
                    if (v2 < v) { v = v2; idx = i2; }
                }
                int p = i * 4 + r;
                if (v < rv[p]) { rv[p] = v; ri[p] = idx; }
            }
        }
    }

    // cross-lane argmin (16 cols per l16 group), then per-wave results to LDS
    #pragma unroll
    for (int p = 0; p < 16; ++p) {
        float v = rv[p]; int idx = ri[p];
        #pragma unroll
        for (int msk = 1; msk < 16; msk <<= 1) {
            float ov = __shfl_xor(v, msk);
            int   oi = __shfl_xor(idx, msk);
            if (ov < v || (ov == v && oi < idx)) { v = ov; idx = oi; }
        }
        if (l16 == 0) {
            int row = (p >> 2) * 16 + quad * 4 + (p & 3);
            s_bv[w][row] = v; s_bi[w][row] = idx;
        }
    }

    __syncthreads();
    // combine 4 waves (each covered a different 512-col range) + histogram
    if (tid < BM) {
        float v = s_bv[0][tid]; int idx = s_bi[0][tid];
        #pragma unroll
        for (int ww = 1; ww < 4; ++ww) {
            float v2 = s_bv[ww][tid]; int i2 = s_bi[ww][tid];
            if (v2 < v || (v2 == v && i2 < idx)) { v = v2; idx = i2; }
        }
        s_bi[0][tid] = idx;
        atomicAdd(&counts[idx], 1u);
    }
    __syncthreads();

    // fused gather: wave w copies rows w*16 .. +16 of z_q from fp32 embeddings
    for (int rr = 0; rr < 16; ++rr) {
        int row = w * 16 + rr;
        int idx = s_bi[0][row];
        const float4* src = (const float4*)(e + (size_t)idx * CDIM);
        float4*       dst = (float4*)(out + (size_t)(m0 + row) * CDIM);
        #pragma unroll
        for (int t = 0; t < 3; ++t)           // 192 float4 per row / 64 lanes
            dst[t * 64 + lane] = src[t * 64 + lane];
    }
}

// ---------- 3) perplexity ----------
__global__ __launch_bounds__(256) void perplexity_k(const unsigned int* __restrict__ counts,
                                                    float* __restrict__ out) {
    int t = threadIdx.x;
    float s = 0.f;
    for (int k = t; k < NCODES; k += 256) {
        float p = (float)counts[k] * (1.0f / (float)NROWS);
        s += p * logf(p + 1e-10f);
    }
    #pragma unroll
    for (int o = 32; o > 0; o >>= 1) s += __shfl_down(s, o);
    __shared__ float red[4];
    if ((t & 63) == 0) red[t >> 6] = s;
    __syncthreads();
    if (t == 0) {
        float tot = red[0] + red[1] + red[2] + red[3];
        out[(size_t)NROWS * CDIM]     = 0.0f;        // vq_loss (eval mode)
        out[(size_t)NROWS * CDIM + 1] = expf(-tot);  // perplexity
    }
}

extern "C" void kernel_launch(void* const* d_in, const int* in_sizes, int n_in,
                              void* d_out, int out_size, void* d_ws, size_t ws_size,
                              hipStream_t stream) {
    const float* z = (const float*)d_in[0];   // [8,4096,768] fp32
    const float* e = (const float*)d_in[1];   // [2048,768]  fp32
    float* out = (float*)d_out;

    // workspace layout (all 16B aligned); total ~25.6 MB
    char* ws = (char*)d_ws;
    unsigned char* z8    = (unsigned char*)ws;  ws += (size_t)NROWS * CDIM;       // 24 MB
    unsigned char* e8t   = (unsigned char*)ws;  ws += (size_t)NCODES * CDIM;      // 1.5 MB (K-major)
    float* enorm         = (float*)ws;          ws += (size_t)NCODES * 4;         // 8 KB
    unsigned int* counts = (unsigned int*)ws;   ws += (size_t)NCODES * 4;         // 8 KB

    convert_fused<<<ZBLOCKS + NCODES, 256, 0, stream>>>(z, e, z8, e8t, enorm, counts);
    gemm_fused<<<NROWS / BM, 256, 0, stream>>>(z8, e8t, enorm, e, out, counts);
    perplexity_k<<<1, 256, 0, stream>>>(counts, out);
}

// Round 5
// 353.624 us; speedup vs baseline: 1.0773x; 1.0773x over previous
//
#include <hip/hip_runtime.h>
#include <hip/hip_bf16.h>
#include <stdint.h>
#include <math.h>

// Problem constants (fixed by reference)
#define NROWS   32768      // 8*4096
#define CDIM    768
#define NCODES  2048
#define BM      64         // rows per block (A-tile resident in LDS)
#define NKB     12         // 768 / 64 (k-blocks of 64)
#define ESCALE  2048.0f    // 2^11: lifts e into e4m3 range
#define INV2ESCALE (2.0f / ESCALE)

typedef __attribute__((ext_vector_type(4))) float f32x4;
typedef __attribute__((ext_vector_type(2))) long v2i64;   // one b128 = 2 MFMA fp8 frags

// Packed fragment layout ("k-packed 64B block"): for a given (row/col, kb),
// byte [q*16 + st*8 + j] holds element k = kb*64 + st*32 + q*8 + j.
// -> lane (quad,l16) reads ONE b128 at +quad*16 and gets both k-steps' 8B frags.

// ---------- helpers ----------
__device__ __forceinline__ void async_load16(const void* gsrc, void* ldst) {
    __builtin_amdgcn_global_load_lds(
        (const __attribute__((address_space(1))) unsigned int*)gsrc,
        (__attribute__((address_space(3))) unsigned int*)ldst,
        16 /*bytes*/, 0 /*offset*/, 0 /*aux*/);
}

__device__ __forceinline__ unsigned int pack4_fp8(float x, float y, float z, float w) {
    int v = __builtin_amdgcn_cvt_pk_fp8_f32(x, y, 0, false);   // bytes 0,1
    v     = __builtin_amdgcn_cvt_pk_fp8_f32(z, w, v, true);    // bytes 2,3
    return (unsigned int)v;
}

// ---------- 1) fused convert: z -> z8p (packed, via LDS), e -> e8p (packed) + ||e||^2 ----------
// z8p: [mblk=512][kb=12][row=64][64B]  (so gemm block's 48KB tile is one linear segment)
// e8p: [kb=12][col=2048][64B]
#define ZCBLOCKS 512
__global__ __launch_bounds__(256) void convert_fused(const float* __restrict__ z,
                                                     const float* __restrict__ e,
                                                     unsigned char* __restrict__ z8p,
                                                     unsigned char* __restrict__ e8p,
                                                     float* __restrict__ enorm,
                                                     unsigned int* __restrict__ counts) {
    int b = blockIdx.x;
    int t = threadIdx.x;
    if (b < ZCBLOCKS) {
        // 64 rows of z: read 12288 float4 linearly, pack into LDS, copy out linearly
        __shared__ unsigned int s_pk[12288];              // 48 KB
        const float4* src = (const float4*)z + (size_t)b * 12288;
        #pragma unroll
        for (int it = 0; it < 48; ++it) {
            int f = it * 256 + t;                         // float4 index 0..12287
            float4 v = src[f];
            int row = f / 192;
            int k0  = (f - row * 192) * 4;                // k of v.x within the row
            int kb  = k0 >> 6;
            int q   = (k0 >> 3) & 3;
            int st  = (k0 >> 5) & 1;
            int hf  = (k0 >> 2) & 1;                      // which half of the 8-j group
            s_pk[kb * 1024 + row * 16 + q * 4 + st * 2 + hf] = pack4_fp8(v.x, v.y, v.z, v.w);
        }
        __syncthreads();
        uint4* dst = (uint4*)(z8p + (size_t)b * 49152);
        const uint4* sp = (const uint4*)s_pk;
        #pragma unroll
        for (int it = 0; it < 12; ++it)
            dst[it * 256 + t] = sp[it * 256 + t];
    } else {
        int col = b - ZCBLOCKS;                           // one code per block
        float s = 0.f;
        if (t < 192) {                                    // float4 #t of this row, k=4t..4t+3
            float4 v = ((const float4*)(e + (size_t)col * CDIM))[t];
            s = v.x * v.x + v.y * v.y + v.z * v.z + v.w * v.w;
            unsigned int pk = pack4_fp8(v.x * ESCALE, v.y * ESCALE,
                                        v.z * ESCALE, v.w * ESCALE);
            int kb = t >> 4, q = (t >> 1) & 3, st = (t >> 3) & 1, hf = t & 1;
            ((unsigned int*)e8p)[(size_t)kb * 32768 + col * 16 + q * 4 + st * 2 + hf] = pk;
        }
        #pragma unroll
        for (int o = 32; o > 0; o >>= 1) s += __shfl_down(s, o);
        __shared__ float red[4];
        if ((t & 63) == 0) red[t >> 6] = s;
        __syncthreads();
        if (t == 0) {
            enorm[col] = red[0] + red[1] + red[2] + red[3];
            counts[col] = 0u;
        }
    }
}

// ---------- 2) A-resident fp8 GEMM + argmin + gather + histogram ----------
// Block owns rows m0..m0+64; A staged ONCE (48KB linear), zero barriers in K-loop.
// Per 64-k iter: 4 ds_read_b128 (dense 1KB, conflict-free) + 4 coalesced global b128
// + 32 MFMA. A pipelined 1 deep, B 2 deep.
__global__ __launch_bounds__(256, 2) void gemm_fused(const unsigned char* __restrict__ z8p,
                                                     const unsigned char* __restrict__ e8p,
                                                     const float* __restrict__ enorm,
                                                     const float* __restrict__ e,
                                                     float* __restrict__ out,
                                                     unsigned int* __restrict__ counts) {
    __shared__ __align__(16) unsigned char As[BM * CDIM];   // 48 KB, [kb][row][64B]
    __shared__ float s_bv[4][BM];
    __shared__ int   s_bi[4][BM];

    const int tid  = threadIdx.x;
    const int m0   = blockIdx.x * BM;
    const int lane = tid & 63;
    const int w    = tid >> 6;
    const int quad = lane >> 4;
    const int l16  = lane & 15;

    // --- stage A-tile: one linear 48 KB copy ---
    #pragma unroll
    for (int t2 = 0; t2 < 12; ++t2) {
        int s = t2 * 256 + tid;
        async_load16(z8p + (size_t)blockIdx.x * 49152 + (size_t)s * 16, &As[s * 16]);
    }
    __syncthreads();                     // the ONLY barrier before the epilogue

    const int wcol0 = w * 512;           // each wave owns 512 cols, 8 chunks of 64
    float rv[16];
    int   ri[16];
    #pragma unroll
    for (int p = 0; p < 16; ++p) { rv[p] = 1e30f; ri[p] = 0; }

    for (int chunk = 0; chunk < 8; ++chunk) {
        const int c0 = wcol0 + chunk * 64;
        const unsigned char* bbase = e8p + ((size_t)(c0 + l16) << 6) + (quad << 4);

        f32x4 acc[4][4] = {};
        v2i64 a[2][4], bb[3][4];

        #define LDA(buf, kb) { _Pragma("unroll") for (int i = 0; i < 4; ++i) { \
            int row = i * 16 + l16; \
            a[buf][i] = *(const v2i64*)&As[(kb) * 4096 + row * 64 + quad * 16]; } }
        #define LDB(buf, kb) { const unsigned char* bp = bbase + (size_t)(kb) * 131072; \
            _Pragma("unroll") for (int j = 0; j < 4; ++j) \
                bb[buf][j] = *(const v2i64*)(bp + j * 1024); }

        LDB(0, 0); LDB(1, 1); LDA(0, 0);
        #pragma unroll
        for (int kb = 0; kb < NKB; ++kb) {
            if (kb < NKB - 1) LDA((kb + 1) & 1, kb + 1);
            if (kb < NKB - 2) LDB((kb + 2) % 3, kb + 2);
            const int ca = kb & 1, cb = kb % 3;
            #pragma unroll
            for (int st = 0; st < 2; ++st)
                #pragma unroll
                for (int i = 0; i < 4; ++i)
                    #pragma unroll
                    for (int j = 0; j < 4; ++j)
                        acc[i][j] = __builtin_amdgcn_mfma_f32_16x16x32_fp8_fp8(
                            a[ca][i][st], bb[cb][j][st], acc[i][j], 0, 0, 0);
        }
        #undef LDA
        #undef LDB

        // per-chunk epilogue: per-lane select only
        float en[4];
        #pragma unroll
        for (int j = 0; j < 4; ++j) en[j] = enorm[c0 + j * 16 + l16];
        const int colbase = c0 + l16;
        #pragma unroll
        for (int i = 0; i < 4; ++i) {
            #pragma unroll
            for (int r = 0; r < 4; ++r) {
                float v   = fmaf(-INV2ESCALE, acc[i][0][r], en[0]);
                int   idx = colbase;
                #pragma unroll
                for (int j = 1; j < 4; ++j) {
                    float v2 = fmaf(-INV2ESCALE, acc[i][j][r], en[j]);
                    int   i2 = colbase + j * 16;
                    if (v2 < v) { v = v2; idx = i2; }
                }
                int p = i * 4 + r;
                if (v < rv[p]) { rv[p] = v; ri[p] = idx; }
            }
        }
    }

    // cross-lane argmin (16 cols per l16 group), then per-wave results to LDS
    #pragma unroll
    for (int p = 0; p < 16; ++p) {
        float v = rv[p]; int idx = ri[p];
        #pragma unroll
        for (int msk = 1; msk < 16; msk <<= 1) {
            float ov = __shfl_xor(v, msk);
            int   oi = __shfl_xor(idx, msk);
            if (ov < v || (ov == v && oi < idx)) { v = ov; idx = oi; }
        }
        if (l16 == 0) {
            int row = (p >> 2) * 16 + quad * 4 + (p & 3);
            s_bv[w][row] = v; s_bi[w][row] = idx;
        }
    }

    __syncthreads();
    // combine 4 waves (each covered a different 512-col range) + histogram
    if (tid < BM) {
        float v = s_bv[0][tid]; int idx = s_bi[0][tid];
        #pragma unroll
        for (int ww = 1; ww < 4; ++ww) {
            float v2 = s_bv[ww][tid]; int i2 = s_bi[ww][tid];
            if (v2 < v || (v2 == v && i2 < idx)) { v = v2; idx = i2; }
        }
        s_bi[0][tid] = idx;
        atomicAdd(&counts[idx], 1u);
    }
    __syncthreads();

    // fused gather: wave w copies rows w*16 .. +16 of z_q from fp32 embeddings
    for (int rr = 0; rr < 16; ++rr) {
        int row = w * 16 + rr;
        int idx = s_bi[0][row];
        const float4* src = (const float4*)(e + (size_t)idx * CDIM);
        float4*       dst = (float4*)(out + (size_t)(m0 + row) * CDIM);
        #pragma unroll
        for (int t = 0; t < 3; ++t)           // 192 float4 per row / 64 lanes
            dst[t * 64 + lane] = src[t * 64 + lane];
    }
}

// ---------- 3) perplexity ----------
__global__ __launch_bounds__(256) void perplexity_k(const unsigned int* __restrict__ counts,
                                                    float* __restrict__ out) {
    int t = threadIdx.x;
    float s = 0.f;
    for (int k = t; k < NCODES; k += 256) {
        float p = (float)counts[k] * (1.0f / (float)NROWS);
        s += p * logf(p + 1e-10f);
    }
    #pragma unroll
    for (int o = 32; o > 0; o >>= 1) s += __shfl_down(s, o);
    __shared__ float red[4];
    if ((t & 63) == 0) red[t >> 6] = s;
    __syncthreads();
    if (t == 0) {
        float tot = red[0] + red[1] + red[2] + red[3];
        out[(size_t)NROWS * CDIM]     = 0.0f;        // vq_loss (eval mode)
        out[(size_t)NROWS * CDIM + 1] = expf(-tot);  // perplexity
    }
}

extern "C" void kernel_launch(void* const* d_in, const int* in_sizes, int n_in,
                              void* d_out, int out_size, void* d_ws, size_t ws_size,
                              hipStream_t stream) {
    const float* z = (const float*)d_in[0];   // [8,4096,768] fp32
    const float* e = (const float*)d_in[1];   // [2048,768]  fp32
    float* out = (float*)d_out;

    // workspace layout (all 16B aligned); total ~25.6 MB
    char* ws = (char*)d_ws;
    unsigned char* z8p   = (unsigned char*)ws;  ws += (size_t)NROWS * CDIM;       // 24 MB (packed)
    unsigned char* e8p   = (unsigned char*)ws;  ws += (size_t)NCODES * CDIM;      // 1.5 MB (packed)
    float* enorm         = (float*)ws;          ws += (size_t)NCODES * 4;         // 8 KB
    unsigned int* counts = (unsigned int*)ws;   ws += (size_t)NCODES * 4;         // 8 KB

    convert_fused<<<ZCBLOCKS + NCODES, 256, 0, stream>>>(z, e, z8p, e8p, enorm, counts);
    gemm_fused<<<NROWS / BM, 256, 0, stream>>>(z8p, e8p, enorm, e, out, counts);
    perplexity_k<<<1, 256, 0, stream>>>(counts, out);
}